// Round 4
// baseline (355.838 us; speedup 1.0000x reference)
//
#include <hip/hip_runtime.h>
#include <hip/hip_cooperative_groups.h>
#include <math.h>

namespace cg = cooperative_groups;

constexpr int H = 32, W = 32, C = 128, G = 4, K = 15, K2 = 225, GC = 32;
constexpr int NPIX = H * W;
constexpr int NOFF = G * K2 * 2;   // 1800
constexpr int NMSK = G * K2;       // 900
constexpr int NTOT = NOFF + NMSK;  // 2700
constexpr int KHID = 32;
constexpr int NBLK = 512;

// workspace layout (float offsets); ws_size = 256MB so plenty of room
constexpr size_t WS_POOLED = 0;        // 128
constexpr size_t WS_ENV    = 128;      // 225 (pad to 256)
constexpr size_t WS_KW     = 384;      // 28800
constexpr size_t WS_PART   = 29184;    // partT[128][512] = 65536
constexpr size_t WS_XPROJ  = 94720;    // 131072
constexpr size_t WS_XDW    = 225792;   // 131072
constexpr size_t WS_OFFS   = 356864;   // 1843200
constexpr size_t WS_MASK   = 2200064;  // 921600
constexpr size_t WS_BT     = 3121664;  // 2752*128 = 352256 (rows >=2700 unused)
// fallback-only regions
constexpr size_t FB_OUTPRE = 3473920;  // 131072
constexpr size_t FB_SCALE  = 3604992;  // 128
constexpr size_t FB_PART   = 3605120;  // 4096

__device__ __forceinline__ float sigmoidf_(float v) { return 1.f / (1.f + expf(-v)); }
__device__ __forceinline__ float siluf_(float v)    { return v / (1.f + expf(-v)); }

struct KParams {
    const float *x, *raw_sigma, *bos, *w_in, *b_in, *w_out, *b_out,
                *dw_k, *dw_b, *pw_w, *pw_b, *off_w, *off_b, *msk_w, *msk_b,
                *k1_w, *k1_b, *k2_w, *k2_b, *k3_w, *k3_b,
                *se1_w, *se1_b, *se2_w, *se2_b;
    float* out;
    float* ws;
};

// =================== persistent mega-kernel (cooperative) ===================
__global__ __launch_bounds__(256, 2) void mega_kernel(KParams P) {
    const int b   = blockIdx.x;   // 0..511
    const int tid = threadIdx.x;
    float* __restrict__ ws = P.ws;
    cg::grid_group grid = cg::this_grid();

    // manually-carved LDS union (50400 B) + persistent outp
    __shared__ __align__(16) unsigned char smraw[50400];
    __shared__ float outp[2][C];

    // ---------------- stage A ----------------
    if (b < 256) {
        // front: 4 pixels per block
        float (*xs)[C] = reinterpret_cast<float (*)[C]>(smraw);          // [4][128]
        float (*ts)[C] = reinterpret_cast<float (*)[C]>(smraw + 2048);   // [4][128]
        int p0 = b * 4;
        int c = tid & 127, pp = tid >> 7;
#pragma unroll
        for (int q = 0; q < 2; q++) {
            int px = pp * 2 + q;
            int p = p0 + px;
            int h = p >> 5, w = p & 31;
            xs[px][c] = P.x[(size_t)p * C + c];
            float y = P.dw_b[c];
#pragma unroll
            for (int dy = 0; dy < 3; dy++) {
                int hh = h + dy - 1;
                if (hh < 0 || hh >= H) continue;
#pragma unroll
                for (int dx = 0; dx < 3; dx++) {
                    int wq = w + dx - 1;
                    if (wq < 0 || wq >= W) continue;
                    y = fmaf(P.x[((size_t)hh * W + wq) * C + c], P.dw_k[(dy * 3 + dx) * C + c], y);
                }
            }
            ts[px][c] = siluf_(y);
        }
        __syncthreads();
        int b0 = pp * 2, b1 = pp * 2 + 1;
        float ap0 = P.b_in[c], ap1 = ap0, ad0 = P.pw_b[c], ad1 = ad0;
        for (int i = 0; i < C; i += 4) {
            float4 x0 = *(const float4*)&xs[b0][i];
            float4 x1 = *(const float4*)&xs[b1][i];
            float4 t0 = *(const float4*)&ts[b0][i];
            float4 t1 = *(const float4*)&ts[b1][i];
            const float* x0f = (const float*)&x0; const float* x1f = (const float*)&x1;
            const float* t0f = (const float*)&t0; const float* t1f = (const float*)&t1;
#pragma unroll
            for (int u = 0; u < 4; u++) {
                float wi = P.w_in[(size_t)(i + u) * C + c];
                float pi = P.pw_w[(size_t)(i + u) * C + c];
                ap0 = fmaf(x0f[u], wi, ap0);
                ap1 = fmaf(x1f[u], wi, ap1);
                ad0 = fmaf(t0f[u], pi, ad0);
                ad1 = fmaf(t1f[u], pi, ad1);
            }
        }
        ws[WS_XPROJ + (size_t)(p0 + b0) * C + c] = ap0;
        ws[WS_XPROJ + (size_t)(p0 + b1) * C + c] = ap1;
        ws[WS_XDW  + (size_t)(p0 + b0) * C + c] = ad0;
        ws[WS_XDW  + (size_t)(p0 + b1) * C + c] = ad1;
    } else {
        int mb = b - 256;
        if (mb < 225) {
            // kernel-MLP point mb
            float* h1 = reinterpret_cast<float*>(smraw);          // [32]
            float* h2 = reinterpret_cast<float*>(smraw + 128);    // [32]
            int i = mb / 15, j = mb % 15;
            float ph = (-0.5f + (float)i * (1.f / 14.f)) * 2.f;
            float pw = (-0.5f + (float)j * (1.f / 14.f)) * 2.f;
            if (tid < KHID)
                h1[tid] = siluf_(fmaf(ph, P.k1_w[tid], fmaf(pw, P.k1_w[KHID + tid], P.k1_b[tid])));
            __syncthreads();
            if (tid < KHID) {
                float a = P.k2_b[tid];
#pragma unroll
                for (int q = 0; q < KHID; q++) a = fmaf(h1[q], P.k2_w[q * KHID + tid], a);
                h2[tid] = siluf_(a);
            }
            __syncthreads();
            if (tid < C) {
                float a = P.k3_b[tid];
#pragma unroll
                for (int q = 0; q < KHID; q++) a = fmaf(h2[q], P.k3_w[q * C + tid], a);
                ws[WS_KW + (size_t)mb * C + tid] = a;
            }
        } else if (mb == 225) {
            // env
            float* red = reinterpret_cast<float*>(smraw);
            float xsg = P.raw_sigma[0];
            float sp = fmaxf(xsg, 0.f) + log1pf(expf(-fabsf(xsg)));
            float sigma = fminf(fmaxf(sp, 0.001f), 0.5f);
            float inv2s2 = 1.f / (2.f * sigma * sigma);
            int i = tid / 15, j = tid % 15;
            float e = 0.f;
            if (tid < K2) {
                float gi = -0.5f + (float)i * (1.f / 14.f);
                float gj = -0.5f + (float)j * (1.f / 14.f);
                e = expf(-(gi * gi + gj * gj) * inv2s2);
            }
            red[tid] = e;
            __syncthreads();
            for (int s = 128; s > 0; s >>= 1) {
                if (tid < s) red[tid] += red[tid + s];
                __syncthreads();
            }
            float esum = fmaxf(red[0], 1e-8f);
            if (tid < K2) ws[WS_ENV + tid] = e / esum;
        }
        // bt transpose: bt[n][k] = W[k][n] (off_w then msk_w columns)
        for (int task = mb * 256 + tid; task < 32 * NTOT; task += 65536) {
            int k4 = task / NTOT;          // 0..31
            int n  = task - k4 * NTOT;
#pragma unroll
            for (int i = 0; i < 4; i++) {
                int kk = k4 * 4 + i;
                float v = (n < NOFF) ? P.off_w[(size_t)kk * NOFF + n]
                                     : P.msk_w[(size_t)kk * NMSK + (n - NOFF)];
                ws[WS_BT + (size_t)n * C + kk] = v;
            }
        }
    }
    grid.sync();

    // ---------------- stage B: offs+mask GEMM, 64x64 tiles, B from bt ----------------
    {
        float (*As)[132] = reinterpret_cast<float (*)[132]>(smraw);   // [64][132]
        for (int t = b; t < 688; t += NBLK) {
            int tm = t / 43, tn = t - tm * 43;
            int p0 = tm * 64, c0 = tn * 64;
            __syncthreads();   // protect LDS reuse
#pragma unroll
            for (int q = 0; q < 8; q++) {
                int flat = q * 256 + tid;       // 0..2047
                int r = flat >> 5;              // 0..63
                int k4 = (flat & 31) * 4;
                float4 v = *(const float4*)&ws[WS_XDW + (size_t)(p0 + r) * C + k4];
                *(float4*)&As[r][k4] = v;
            }
            __syncthreads();
            int tx = tid & 15, ty = tid >> 4;
            int r0 = ty * 4;
            int n0 = c0 + tx * 4;
            float acc[4][4];
#pragma unroll
            for (int i = 0; i < 4; i++)
#pragma unroll
                for (int j = 0; j < 4; j++) acc[i][j] = 0.f;
            const float* btb = &ws[WS_BT + (size_t)n0 * C];
            for (int kk = 0; kk < C; kk += 4) {
                float4 A0 = *(const float4*)&As[r0 + 0][kk];
                float4 A1 = *(const float4*)&As[r0 + 1][kk];
                float4 A2 = *(const float4*)&As[r0 + 2][kk];
                float4 A3 = *(const float4*)&As[r0 + 3][kk];
                float4 B0 = *(const float4*)&btb[0 * C + kk];
                float4 B1 = *(const float4*)&btb[1 * C + kk];
                float4 B2 = *(const float4*)&btb[2 * C + kk];
                float4 B3 = *(const float4*)&btb[3 * C + kk];
                const float* Af[4] = {(const float*)&A0, (const float*)&A1, (const float*)&A2, (const float*)&A3};
                const float* Bf[4] = {(const float*)&B0, (const float*)&B1, (const float*)&B2, (const float*)&B3};
#pragma unroll
                for (int i = 0; i < 4; i++)
#pragma unroll
                    for (int j = 0; j < 4; j++) {
                        float a = acc[i][j];
                        a = fmaf(Af[i][0], Bf[j][0], a);
                        a = fmaf(Af[i][1], Bf[j][1], a);
                        a = fmaf(Af[i][2], Bf[j][2], a);
                        a = fmaf(Af[i][3], Bf[j][3], a);
                        acc[i][j] = a;
                    }
            }
            int colbase = n0;
            if (colbase < NTOT) {
                float bias[4], sc[4];
                float* obase;
                int ostride;
                if (colbase < NOFF) {
                    float s = P.bos[0];
#pragma unroll
                    for (int j = 0; j < 4; j++) { bias[j] = P.off_b[colbase + j]; sc[j] = s; }
                    obase = ws + WS_OFFS + colbase; ostride = NOFF;
                } else {
                    int m0 = colbase - NOFF;
#pragma unroll
                    for (int j = 0; j < 4; j++) { bias[j] = P.msk_b[m0 + j]; sc[j] = ws[WS_ENV + (m0 + j) % K2]; }
                    obase = ws + WS_MASK + m0; ostride = NMSK;
                }
#pragma unroll
                for (int i = 0; i < 4; i++) {
                    size_t row = (size_t)(p0 + ty * 4 + i);
                    float4 r0v = make_float4((acc[i][0] + bias[0]) * sc[0], (acc[i][1] + bias[1]) * sc[1],
                                             (acc[i][2] + bias[2]) * sc[2], (acc[i][3] + bias[3]) * sc[3]);
                    *(float4*)&obase[row * ostride] = r0v;
                }
            }
        }
    }
    grid.sync();

    // ---------------- stage C: sampler (2 px per block, 1:1) ----------------
    {
        float*   attn = reinterpret_cast<float*>(smraw);             // [2][900]
        float4*  wgt  = reinterpret_cast<float4*>(smraw + 7200);     // [2][900]
        ushort4* loc  = reinterpret_cast<ushort4*>(smraw + 36000);   // [2][900]
        int p0 = b * 2;
        int h = p0 >> 5;

        // phase 1: softmax per (px,g) on 8 half-waves
        {
            int half = tid >> 5;
            int l32 = tid & 31;
            int px = half >> 2, g = half & 3;
            const float* mrow = ws + WS_MASK + (size_t)(p0 + px) * NMSK + g * K2;
            float v[8];
            float mx = -1e30f;
#pragma unroll
            for (int q = 0; q < 8; q++) {
                int k = l32 + q * 32;
                v[q] = (k < K2) ? mrow[k] : -1e30f;
                mx = fmaxf(mx, v[q]);
            }
#pragma unroll
            for (int s = 16; s > 0; s >>= 1) mx = fmaxf(mx, __shfl_xor(mx, s));
            float sum = 0.f;
#pragma unroll
            for (int q = 0; q < 8; q++) {
                int k = l32 + q * 32;
                v[q] = (k < K2) ? expf(v[q] - mx) : 0.f;
                sum += v[q];
            }
#pragma unroll
            for (int s = 16; s > 0; s >>= 1) sum += __shfl_xor(sum, s);
            float inv = 1.f / sum;
#pragma unroll
            for (int q = 0; q < 8; q++) {
                int k = l32 + q * 32;
                if (k < K2) attn[px * NMSK + g * K2 + k] = v[q] * inv;
            }
        }
        __syncthreads();

        // phase 2: bilinear weights + packed corner pixel indices
        for (int e = tid; e < 2 * NMSK; e += 256) {
            int px = (e >= NMSK) ? 1 : 0;
            int m = e - px * NMSK;
            int g = m / K2;
            int k = m - g * K2;
            int p = p0 + px;
            int w = p & 31;
            float2 o = *(const float2*)&ws[WS_OFFS + (size_t)p * NOFF + m * 2];
            float abs_h = (float)(h + k / 15 - 7) + o.x;
            float abs_w = (float)(w + k % 15 - 7) + o.y;
            float validf = (abs_h < 0.f || abs_h > 31.f || abs_w < 0.f || abs_w > 31.f) ? 0.f : 1.f;
            float ah = fminf(fmaxf(abs_h, 0.f), 31.f);
            float aw = fminf(fmaxf(abs_w, 0.f), 31.f);
            int hf = (int)ah, wf = (int)aw;
            int hc = min(hf + 1, 31), wc = min(wf + 1, 31);
            float hwt = ah - (float)hf, wwt = aw - (float)wf;
            float a = attn[px * NMSK + m] * validf;
            float u0 = 1.f - hwt, u1 = 1.f - wwt;
            wgt[px * NMSK + m] = make_float4(a * u0 * u1, a * u0 * wwt, a * hwt * u1, a * hwt * wwt);
            loc[px * NMSK + m] = make_ushort4((unsigned short)(hf * W + wf), (unsigned short)(hf * W + wc),
                                              (unsigned short)(hc * W + wf), (unsigned short)(hc * W + wc));
        }
        __syncthreads();

        // phase 3: px(2) x g(4) x s(4) x cq(8), shuffle-reduce over s
        {
            int cq = tid & 7;
            int s  = (tid >> 3) & 3;
            int g  = (tid >> 5) & 3;
            int px = tid >> 7;
            int k0 = (s * K2) >> 2;
            int k1 = ((s + 1) * K2) >> 2;
            const float* xpg = ws + WS_XPROJ + g * GC + cq * 4;
            const float* kwg = ws + WS_KW + (size_t)g * (K2 * GC) + cq * 4;
            float4 acc = make_float4(0.f, 0.f, 0.f, 0.f);
#pragma unroll 2
            for (int k = k0; k < k1; k++) {
                int m = g * K2 + k;
                ushort4 L  = loc[px * NMSK + m];
                float4  Wv = wgt[px * NMSK + m];
                float4 x00 = *(const float4*)(xpg + (int)L.x * C);
                float4 x01 = *(const float4*)(xpg + (int)L.y * C);
                float4 x10 = *(const float4*)(xpg + (int)L.z * C);
                float4 x11 = *(const float4*)(xpg + (int)L.w * C);
                float4 kw4 = *(const float4*)(kwg + k * GC);
                float sx = fmaf(Wv.w, x11.x, fmaf(Wv.z, x10.x, fmaf(Wv.y, x01.x, Wv.x * x00.x)));
                float sy = fmaf(Wv.w, x11.y, fmaf(Wv.z, x10.y, fmaf(Wv.y, x01.y, Wv.x * x00.y)));
                float sz = fmaf(Wv.w, x11.z, fmaf(Wv.z, x10.z, fmaf(Wv.y, x01.z, Wv.x * x00.z)));
                float sw = fmaf(Wv.w, x11.w, fmaf(Wv.z, x10.w, fmaf(Wv.y, x01.w, Wv.x * x00.w)));
                acc.x = fmaf(kw4.x, sx, acc.x);
                acc.y = fmaf(kw4.y, sy, acc.y);
                acc.z = fmaf(kw4.z, sz, acc.z);
                acc.w = fmaf(kw4.w, sw, acc.w);
            }
            acc.x += __shfl_xor(acc.x, 8);  acc.y += __shfl_xor(acc.y, 8);
            acc.z += __shfl_xor(acc.z, 8);  acc.w += __shfl_xor(acc.w, 8);
            acc.x += __shfl_xor(acc.x, 16); acc.y += __shfl_xor(acc.y, 16);
            acc.z += __shfl_xor(acc.z, 16); acc.w += __shfl_xor(acc.w, 16);
            if (s == 0)
                *(float4*)&outp[px][g * GC + cq * 4] = acc;
        }
        __syncthreads();
        if (tid < C)
            ws[WS_PART + (size_t)tid * NBLK + b] = outp[0][tid] + outp[1][tid];
    }
    grid.sync();

    // ---------------- stage D1: column-parallel pooled reduce ----------------
    if (b < C) {
        float* red = reinterpret_cast<float*>(smraw);
        float acc = ws[WS_PART + (size_t)b * NBLK + tid] + ws[WS_PART + (size_t)b * NBLK + 256 + tid];
        red[tid] = acc;
        __syncthreads();
        for (int s = 128; s > 0; s >>= 1) {
            if (tid < s) red[tid] += red[tid + s];
            __syncthreads();
        }
        if (tid == 0) ws[WS_POOLED + b] = red[0] * (1.f / 1024.f);
    }
    grid.sync();

    // ---------------- stage D2 (redundant per block): SE MLP; stage E: final ----------------
    {
        float* pl  = reinterpret_cast<float*>(smraw + 1024);  // [128]
        float* hid = reinterpret_cast<float*>(smraw + 1536);  // [32]
        float* sc  = reinterpret_cast<float*>(smraw + 1664);  // [128]
        float (*vb)[C] = reinterpret_cast<float (*)[C]>(smraw + 2176);  // [2][128]
        if (tid < C) pl[tid] = ws[WS_POOLED + tid];
        __syncthreads();
        if (tid < KHID) {
            float a = P.se1_b[tid];
            for (int cc = 0; cc < C; cc++) a = fmaf(pl[cc], P.se1_w[cc * KHID + tid], a);
            hid[tid] = siluf_(a);
        }
        __syncthreads();
        if (tid < C) {
            float a = P.se2_b[tid];
#pragma unroll
            for (int q = 0; q < KHID; q++) a = fmaf(hid[q], P.se2_w[q * C + tid], a);
            float sv = sigmoidf_(a);
            sc[tid] = sv;
            vb[0][tid] = outp[0][tid] * sv;
            vb[1][tid] = outp[1][tid] * sv;
        }
        __syncthreads();
        int c = tid & 127, px = tid >> 7;
        float acc = P.b_out[c];
        for (int i = 0; i < C; i += 4) {
            float4 vv = *(const float4*)&vb[px][i];
            const float* vf = (const float*)&vv;
#pragma unroll
            for (int u = 0; u < 4; u++)
                acc = fmaf(vf[u], P.w_out[(size_t)(i + u) * C + c], acc);
        }
        P.out[(size_t)(b * 2 + px) * C + c] = acc;
    }
}

// =================== fallback chain (round-3, known-good) ===================
__device__ __forceinline__ void fb_mlp_point(int k2i, int lane,
        const float* __restrict__ k1_w, const float* __restrict__ k1_b,
        const float* __restrict__ k2_w, const float* __restrict__ k2_b,
        const float* __restrict__ k3_w, const float* __restrict__ k3_b,
        float* __restrict__ ws) {
    int i = k2i / 15, j = k2i % 15;
    float ph = (-0.5f + (float)i * (1.f / 14.f)) * 2.f;
    float pw = (-0.5f + (float)j * (1.f / 14.f)) * 2.f;
    float h1[KHID], h2[KHID];
#pragma unroll
    for (int m = 0; m < KHID; m++)
        h1[m] = siluf_(fmaf(ph, k1_w[m], fmaf(pw, k1_w[KHID + m], k1_b[m])));
#pragma unroll
    for (int m = 0; m < KHID; m++) {
        float a = k2_b[m];
#pragma unroll
        for (int q = 0; q < KHID; q++) a = fmaf(h1[q], k2_w[q * KHID + m], a);
        h2[m] = siluf_(a);
    }
#pragma unroll
    for (int t = 0; t < 2; t++) {
        int col = lane + t * 64;
        float a = k3_b[col];
#pragma unroll
        for (int q = 0; q < KHID; q++) a = fmaf(h2[q], k3_w[q * C + col], a);
        ws[WS_KW + (size_t)k2i * C + col] = a;
    }
}

__global__ __launch_bounds__(256) void fb_prep(const float* __restrict__ raw_sigma,
        const float* __restrict__ k1_w, const float* __restrict__ k1_b,
        const float* __restrict__ k2_w, const float* __restrict__ k2_b,
        const float* __restrict__ k3_w, const float* __restrict__ k3_b,
        float* __restrict__ ws) {
    int tid = threadIdx.x;
    if (blockIdx.x == 0) {
        __shared__ float red[256];
        float xs = raw_sigma[0];
        float sp = fmaxf(xs, 0.f) + log1pf(expf(-fabsf(xs)));
        float sigma = fminf(fmaxf(sp, 0.001f), 0.5f);
        float inv2s2 = 1.f / (2.f * sigma * sigma);
        int i = tid / 15, j = tid % 15;
        float e = 0.f;
        if (tid < K2) {
            float gi = -0.5f + (float)i * (1.f / 14.f);
            float gj = -0.5f + (float)j * (1.f / 14.f);
            e = expf(-(gi * gi + gj * gj) * inv2s2);
        }
        red[tid] = e;
        __syncthreads();
        for (int s = 128; s > 0; s >>= 1) {
            if (tid < s) red[tid] += red[tid + s];
            __syncthreads();
        }
        float esum = fmaxf(red[0], 1e-8f);
        if (tid < K2) ws[WS_ENV + tid] = e / esum;
        if (tid < 64) fb_mlp_point(224, tid, k1_w, k1_b, k2_w, k2_b, k3_w, k3_b, ws);
    } else {
        int k2i = (blockIdx.x - 1) * 4 + (tid >> 6);
        fb_mlp_point(k2i, tid & 63, k1_w, k1_b, k2_w, k2_b, k3_w, k3_b, ws);
    }
}

__global__ __launch_bounds__(256) void fb_front(const float* __restrict__ x,
        const float* __restrict__ w_in, const float* __restrict__ b_in,
        const float* __restrict__ dw_k, const float* __restrict__ dw_b,
        const float* __restrict__ pw_w, const float* __restrict__ pw_b,
        float* __restrict__ ws) {
    int p0 = blockIdx.x * 4;
    int tid = threadIdx.x;
    int c = tid & 127;
    int pp = tid >> 7;
    __shared__ float xs[4][C], ts[4][C];
#pragma unroll
    for (int q = 0; q < 2; q++) {
        int px = pp * 2 + q;
        int p = p0 + px;
        int h = p >> 5, w = p & 31;
        xs[px][c] = x[(size_t)p * C + c];
        float y = dw_b[c];
#pragma unroll
        for (int dy = 0; dy < 3; dy++) {
            int hh = h + dy - 1;
            if (hh < 0 || hh >= H) continue;
#pragma unroll
            for (int dx = 0; dx < 3; dx++) {
                int wq = w + dx - 1;
                if (wq < 0 || wq >= W) continue;
                y = fmaf(x[((size_t)hh * W + wq) * C + c], dw_k[(dy * 3 + dx) * C + c], y);
            }
        }
        ts[px][c] = siluf_(y);
    }
    __syncthreads();
    float ap0 = b_in[c], ap1 = b_in[c], ad0 = pw_b[c], ad1 = pw_b[c];
    int b0 = pp * 2, b1 = pp * 2 + 1;
    for (int i = 0; i < C; i += 4) {
#pragma unroll
        for (int u = 0; u < 4; u++) {
            float wi = w_in[(size_t)(i + u) * C + c];
            float pi = pw_w[(size_t)(i + u) * C + c];
            ap0 = fmaf(xs[b0][i + u], wi, ap0);
            ap1 = fmaf(xs[b1][i + u], wi, ap1);
            ad0 = fmaf(ts[b0][i + u], pi, ad0);
            ad1 = fmaf(ts[b1][i + u], pi, ad1);
        }
    }
    ws[WS_XPROJ + (size_t)(p0 + b0) * C + c] = ap0;
    ws[WS_XPROJ + (size_t)(p0 + b1) * C + c] = ap1;
    ws[WS_XDW  + (size_t)(p0 + b0) * C + c] = ad0;
    ws[WS_XDW  + (size_t)(p0 + b1) * C + c] = ad1;
}

__global__ __launch_bounds__(256) void fb_gemm(const float* __restrict__ A,
        const float* __restrict__ off_w, const float* __restrict__ off_b,
        const float* __restrict__ msk_w, const float* __restrict__ msk_b,
        const float* __restrict__ bos, const float* __restrict__ env,
        float* __restrict__ offs_out, float* __restrict__ mask_out) {
    __shared__ float At[32][72];
    __shared__ float Bs[32][64];
    int tid = threadIdx.x;
    int c0 = blockIdx.x * 64;
    int p0 = blockIdx.y * 64;
    int tx = tid & 15, ty = tid >> 4;
    float acc[4][4];
#pragma unroll
    for (int i = 0; i < 4; i++)
#pragma unroll
        for (int j = 0; j < 4; j++) acc[i][j] = 0.f;
    int cL = (tid * 4) & 63;
    int kL = (tid * 4) >> 6;
    int cB = c0 + cL;
    const float* bptr = nullptr; int bstride = 0;
    if (cB < NOFF)       { bptr = off_w + cB;          bstride = NOFF; }
    else if (cB < NTOT)  { bptr = msk_w + (cB - NOFF); bstride = NMSK; }
    int rA = tid >> 3, k4A = (tid & 7) * 4;
    for (int kt = 0; kt < C; kt += 32) {
        if (kt) __syncthreads();
#pragma unroll
        for (int pass = 0; pass < 2; pass++) {
            int r = rA + pass * 32;
            float4 v = *(const float4*)&A[(size_t)(p0 + r) * C + kt + k4A];
            At[k4A + 0][r] = v.x; At[k4A + 1][r] = v.y;
            At[k4A + 2][r] = v.z; At[k4A + 3][r] = v.w;
            int k = kL + pass * 16;
            float4 bv = make_float4(0.f, 0.f, 0.f, 0.f);
            if (bptr) bv = *(const float4*)&bptr[(size_t)(kt + k) * bstride];
            *(float4*)&Bs[k][cL] = bv;
        }
        __syncthreads();
#pragma unroll
        for (int k = 0; k < 32; k++) {
            float4 a4 = *(const float4*)&At[k][ty * 4];
            float4 b4 = *(const float4*)&Bs[k][tx * 4];
            const float av[4] = {a4.x, a4.y, a4.z, a4.w};
            const float bv[4] = {b4.x, b4.y, b4.z, b4.w};
#pragma unroll
            for (int i = 0; i < 4; i++)
#pragma unroll
                for (int j = 0; j < 4; j++)
                    acc[i][j] = fmaf(av[i], bv[j], acc[i][j]);
        }
    }
    int colbase = c0 + tx * 4;
    if (colbase >= NTOT) return;
    float bias[4], sc[4];
    float* obase; int ostride;
    if (colbase < NOFF) {
        float s = bos[0];
#pragma unroll
        for (int j = 0; j < 4; j++) { bias[j] = off_b[colbase + j]; sc[j] = s; }
        obase = offs_out + colbase; ostride = NOFF;
    } else {
        int m0 = colbase - NOFF;
#pragma unroll
        for (int j = 0; j < 4; j++) { bias[j] = msk_b[m0 + j]; sc[j] = env[(m0 + j) % K2]; }
        obase = mask_out + m0; ostride = NMSK;
    }
#pragma unroll
    for (int i = 0; i < 4; i++) {
        size_t row = (size_t)(p0 + ty * 4 + i);
        float4 r0 = make_float4((acc[i][0] + bias[0]) * sc[0], (acc[i][1] + bias[1]) * sc[1],
                                (acc[i][2] + bias[2]) * sc[2], (acc[i][3] + bias[3]) * sc[3]);
        *(float4*)&obase[row * ostride] = r0;
    }
}

__global__ __launch_bounds__(256) void fb_sampler(const float* __restrict__ ws_offs,
        const float* __restrict__ ws_mask, const float* __restrict__ xproj,
        const float* __restrict__ kwf, float* __restrict__ outpre) {
    int p0 = blockIdx.x * 2;
    int h = p0 >> 5;
    int tid = threadIdx.x;
    __shared__ float   attn_s[2][NMSK];
    __shared__ float4  wgt_s[2][NMSK];
    __shared__ ushort4 loc_s[2][NMSK];
    {
        int half = tid >> 5;
        int l32 = tid & 31;
        int px = half >> 2, g = half & 3;
        const float* mrow = ws_mask + (size_t)(p0 + px) * NMSK + g * K2;
        float v[8];
        float mx = -1e30f;
#pragma unroll
        for (int q = 0; q < 8; q++) {
            int k = l32 + q * 32;
            v[q] = (k < K2) ? mrow[k] : -1e30f;
            mx = fmaxf(mx, v[q]);
        }
#pragma unroll
        for (int s = 16; s > 0; s >>= 1) mx = fmaxf(mx, __shfl_xor(mx, s));
        float sum = 0.f;
#pragma unroll
        for (int q = 0; q < 8; q++) {
            int k = l32 + q * 32;
            v[q] = (k < K2) ? expf(v[q] - mx) : 0.f;
            sum += v[q];
        }
#pragma unroll
        for (int s = 16; s > 0; s >>= 1) sum += __shfl_xor(sum, s);
        float inv = 1.f / sum;
#pragma unroll
        for (int q = 0; q < 8; q++) {
            int k = l32 + q * 32;
            if (k < K2) attn_s[px][g * K2 + k] = v[q] * inv;
        }
    }
    __syncthreads();
    for (int e = tid; e < 2 * NMSK; e += 256) {
        int px = (e >= NMSK) ? 1 : 0;
        int m = e - px * NMSK;
        int g = m / K2;
        int k = m - g * K2;
        int p = p0 + px;
        int w = p & 31;
        float2 o = *(const float2*)&ws_offs[(size_t)p * NOFF + m * 2];
        float abs_h = (float)(h + k / 15 - 7) + o.x;
        float abs_w = (float)(w + k % 15 - 7) + o.y;
        float validf = (abs_h < 0.f || abs_h > 31.f || abs_w < 0.f || abs_w > 31.f) ? 0.f : 1.f;
        float ah = fminf(fmaxf(abs_h, 0.f), 31.f);
        float aw = fminf(fmaxf(abs_w, 0.f), 31.f);
        int hf = (int)ah, wf = (int)aw;
        int hc = min(hf + 1, 31), wc = min(wf + 1, 31);
        float hwt = ah - (float)hf, wwt = aw - (float)wf;
        float a = attn_s[px][m] * validf;
        float u0 = 1.f - hwt, u1 = 1.f - wwt;
        wgt_s[px][m] = make_float4(a * u0 * u1, a * u0 * wwt, a * hwt * u1, a * hwt * wwt);
        loc_s[px][m] = make_ushort4((unsigned short)(hf * W + wf), (unsigned short)(hf * W + wc),
                                    (unsigned short)(hc * W + wf), (unsigned short)(hc * W + wc));
    }
    __syncthreads();
    {
        int cq = tid & 7;
        int s  = (tid >> 3) & 3;
        int g  = (tid >> 5) & 3;
        int px = tid >> 7;
        int k0 = (s * K2) >> 2;
        int k1 = ((s + 1) * K2) >> 2;
        const float* xpg = xproj + g * GC + cq * 4;
        const float* kwg = kwf + (size_t)g * (K2 * GC) + cq * 4;
        float4 acc = make_float4(0.f, 0.f, 0.f, 0.f);
        for (int k = k0; k < k1; k++) {
            int m = g * K2 + k;
            ushort4 L  = loc_s[px][m];
            float4  Wv = wgt_s[px][m];
            float4 x00 = *(const float4*)(xpg + (int)L.x * C);
            float4 x01 = *(const float4*)(xpg + (int)L.y * C);
            float4 x10 = *(const float4*)(xpg + (int)L.z * C);
            float4 x11 = *(const float4*)(xpg + (int)L.w * C);
            float4 kw4 = *(const float4*)(kwg + k * GC);
            float sx = fmaf(Wv.w, x11.x, fmaf(Wv.z, x10.x, fmaf(Wv.y, x01.x, Wv.x * x00.x)));
            float sy = fmaf(Wv.w, x11.y, fmaf(Wv.z, x10.y, fmaf(Wv.y, x01.y, Wv.x * x00.y)));
            float sz = fmaf(Wv.w, x11.z, fmaf(Wv.z, x10.z, fmaf(Wv.y, x01.z, Wv.x * x00.z)));
            float sw = fmaf(Wv.w, x11.w, fmaf(Wv.z, x10.w, fmaf(Wv.y, x01.w, Wv.x * x00.w)));
            acc.x = fmaf(kw4.x, sx, acc.x);
            acc.y = fmaf(kw4.y, sy, acc.y);
            acc.z = fmaf(kw4.z, sz, acc.z);
            acc.w = fmaf(kw4.w, sw, acc.w);
        }
        acc.x += __shfl_xor(acc.x, 8);  acc.y += __shfl_xor(acc.y, 8);
        acc.z += __shfl_xor(acc.z, 8);  acc.w += __shfl_xor(acc.w, 8);
        acc.x += __shfl_xor(acc.x, 16); acc.y += __shfl_xor(acc.y, 16);
        acc.z += __shfl_xor(acc.z, 16); acc.w += __shfl_xor(acc.w, 16);
        if (s == 0)
            *(float4*)&outpre[(size_t)(p0 + px) * C + g * GC + cq * 4] = acc;
    }
}

__global__ void fb_reduce1(const float* __restrict__ outpre, float* __restrict__ part) {
    int b = blockIdx.x;
    int c = threadIdx.x;
    float s = 0.f;
    for (int q = 0; q < 32; q++) s += outpre[(size_t)(b * 32 + q) * C + c];
    part[(size_t)b * C + c] = s;
}

__global__ void fb_se(const float* __restrict__ part,
        const float* __restrict__ se1_w, const float* __restrict__ se1_b,
        const float* __restrict__ se2_w, const float* __restrict__ se2_b,
        float* __restrict__ scale_out) {
    __shared__ float pooled[C];
    __shared__ float hid[KHID];
    int tid = threadIdx.x;
    float s = 0.f;
    for (int b = 0; b < 32; b++) s += part[(size_t)b * C + tid];
    pooled[tid] = s * (1.f / 1024.f);
    __syncthreads();
    if (tid < KHID) {
        float a = se1_b[tid];
        for (int cc = 0; cc < C; cc++) a = fmaf(pooled[cc], se1_w[cc * KHID + tid], a);
        hid[tid] = siluf_(a);
    }
    __syncthreads();
    float a = se2_b[tid];
#pragma unroll
    for (int q = 0; q < KHID; q++) a = fmaf(hid[q], se2_w[q * C + tid], a);
    scale_out[tid] = sigmoidf_(a);
}

__global__ __launch_bounds__(256) void fb_final(const float* __restrict__ outpre,
        const float* __restrict__ scale,
        const float* __restrict__ w_out, const float* __restrict__ b_out,
        float* __restrict__ out) {
    int p0 = blockIdx.x * 4;
    int tid = threadIdx.x;
    int c = tid & 127;
    int pp = tid >> 7;
    __shared__ float v[4][C];
    float scv = scale[c];
#pragma unroll
    for (int q = 0; q < 2; q++) {
        int px = pp * 2 + q;
        v[px][c] = outpre[(size_t)(p0 + px) * C + c] * scv;
    }
    __syncthreads();
    float a0 = b_out[c], a1 = b_out[c];
    int b0 = pp * 2, b1 = pp * 2 + 1;
    for (int i = 0; i < C; i += 4) {
#pragma unroll
        for (int u = 0; u < 4; u++) {
            float wv = w_out[(size_t)(i + u) * C + c];
            a0 = fmaf(v[b0][i + u], wv, a0);
            a1 = fmaf(v[b1][i + u], wv, a1);
        }
    }
    out[(size_t)(p0 + b0) * C + c] = a0;
    out[(size_t)(p0 + b1) * C + c] = a1;
}

extern "C" void kernel_launch(void* const* d_in, const int* in_sizes, int n_in,
                              void* d_out, int out_size, void* d_ws, size_t ws_size,
                              hipStream_t stream) {
    const float* x         = (const float*)d_in[0];
    const float* raw_sigma = (const float*)d_in[1];
    const float* bos       = (const float*)d_in[2];
    const float* w_in      = (const float*)d_in[3];
    const float* b_in      = (const float*)d_in[4];
    const float* w_out     = (const float*)d_in[5];
    const float* b_out     = (const float*)d_in[6];
    const float* dw_k      = (const float*)d_in[7];
    const float* dw_b      = (const float*)d_in[8];
    const float* pw_w      = (const float*)d_in[9];
    const float* pw_b      = (const float*)d_in[10];
    const float* off_w     = (const float*)d_in[11];
    const float* off_b     = (const float*)d_in[12];
    const float* msk_w     = (const float*)d_in[13];
    const float* msk_b     = (const float*)d_in[14];
    const float* k1_w      = (const float*)d_in[15];
    const float* k1_b      = (const float*)d_in[16];
    const float* k2_w      = (const float*)d_in[17];
    const float* k2_b      = (const float*)d_in[18];
    const float* k3_w      = (const float*)d_in[19];
    const float* k3_b      = (const float*)d_in[20];
    const float* se1_w     = (const float*)d_in[21];
    const float* se1_b     = (const float*)d_in[22];
    const float* se2_w     = (const float*)d_in[23];
    const float* se2_b     = (const float*)d_in[24];

    float* ws  = (float*)d_ws;
    float* out = (float*)d_out;

    KParams P{x, raw_sigma, bos, w_in, b_in, w_out, b_out, dw_k, dw_b, pw_w, pw_b,
              off_w, off_b, msk_w, msk_b, k1_w, k1_b, k2_w, k2_b, k3_w, k3_b,
              se1_w, se1_b, se2_w, se2_b, out, ws};
    void* args[] = {&P};
    hipError_t err = hipLaunchCooperativeKernel((const void*)mega_kernel, dim3(NBLK),
                                                dim3(256), args, 0, stream);
    if (err != hipSuccess) {
        // fallback: round-3 multi-kernel chain
        fb_prep<<<57, 256, 0, stream>>>(raw_sigma, k1_w, k1_b, k2_w, k2_b, k3_w, k3_b, ws);
        fb_front<<<NPIX / 4, 256, 0, stream>>>(x, w_in, b_in, dw_k, dw_b, pw_w, pw_b, ws);
        dim3 gg((NTOT + 63) / 64, NPIX / 64);
        fb_gemm<<<gg, 256, 0, stream>>>(ws + WS_XDW, off_w, off_b, msk_w, msk_b, bos,
                                        ws + WS_ENV, ws + WS_OFFS, ws + WS_MASK);
        fb_sampler<<<NPIX / 2, 256, 0, stream>>>(ws + WS_OFFS, ws + WS_MASK, ws + WS_XPROJ,
                                                 ws + WS_KW, ws + FB_OUTPRE);
        fb_reduce1<<<32, C, 0, stream>>>(ws + FB_OUTPRE, ws + FB_PART);
        fb_se<<<1, C, 0, stream>>>(ws + FB_PART, se1_w, se1_b, se2_w, se2_b, ws + FB_SCALE);
        fb_final<<<NPIX / 4, 256, 0, stream>>>(ws + FB_OUTPRE, ws + FB_SCALE, w_out, b_out, out);
    }
}

// Round 5
// 79.634 us; speedup vs baseline: 4.4684x; 4.4684x over previous
//
#include <hip/hip_runtime.h>
#include <math.h>

constexpr int H = 32, W = 32, C = 128, G = 4, K = 15, K2 = 225, GC = 32;
constexpr int NPIX = H * W;
constexpr int NOFF = G * K2 * 2;   // 1800
constexpr int NMSK = G * K2;       // 900
constexpr int NTOT = NOFF + NMSK;  // 2700
constexpr int KHID = 32;

// workspace layout (float offsets)
constexpr size_t WS_ENV    = 128;      // 225 (pad)
constexpr size_t WS_KW     = 384;      // 28800
constexpr size_t WS_PART   = 29184;    // partial[512][128] = 65536
constexpr size_t WS_XPROJ  = 94720;    // 131072
constexpr size_t WS_XDW    = 225792;   // 131072
constexpr size_t WS_OFFS   = 356864;   // 1843200
constexpr size_t WS_MASK   = 2200064;  // 921600
constexpr size_t WS_OUTPRE = 3121664;  // 131072

__device__ __forceinline__ float sigmoidf_(float v) { return 1.f / (1.f + expf(-v)); }
__device__ __forceinline__ float siluf_(float v)    { return v / (1.f + expf(-v)); }

// ---------------- K1: front (blocks 0-255) + kernel-MLP/env (blocks 256-312) ----------------
__device__ __forceinline__ void mlp_point(int k2i, int lane,
        const float* __restrict__ k1_w, const float* __restrict__ k1_b,
        const float* __restrict__ k2_w, const float* __restrict__ k2_b,
        const float* __restrict__ k3_w, const float* __restrict__ k3_b,
        float* __restrict__ ws) {
    int i = k2i / 15, j = k2i % 15;
    float ph = (-0.5f + (float)i * (1.f / 14.f)) * 2.f;
    float pw = (-0.5f + (float)j * (1.f / 14.f)) * 2.f;
    float h1[KHID], h2[KHID];
#pragma unroll
    for (int m = 0; m < KHID; m++)
        h1[m] = siluf_(fmaf(ph, k1_w[m], fmaf(pw, k1_w[KHID + m], k1_b[m])));
#pragma unroll
    for (int m = 0; m < KHID; m++) {
        float a = k2_b[m];
#pragma unroll
        for (int q = 0; q < KHID; q++) a = fmaf(h1[q], k2_w[q * KHID + m], a);
        h2[m] = siluf_(a);
    }
#pragma unroll
    for (int t = 0; t < 2; t++) {
        int col = lane + t * 64;
        float a = k3_b[col];
#pragma unroll
        for (int q = 0; q < KHID; q++) a = fmaf(h2[q], k3_w[q * C + col], a);
        ws[WS_KW + (size_t)k2i * C + col] = a;  // kw[g][k][c] = flat[g*7200 + k*32 + c]
    }
}

__global__ __launch_bounds__(256) void prep_front_kernel(const float* __restrict__ x,
        const float* __restrict__ raw_sigma,
        const float* __restrict__ w_in, const float* __restrict__ b_in,
        const float* __restrict__ dw_k, const float* __restrict__ dw_b,
        const float* __restrict__ pw_w, const float* __restrict__ pw_b,
        const float* __restrict__ k1_w, const float* __restrict__ k1_b,
        const float* __restrict__ k2_w, const float* __restrict__ k2_b,
        const float* __restrict__ k3_w, const float* __restrict__ k3_b,
        float* __restrict__ ws) {
    int tid = threadIdx.x;
    int b = blockIdx.x;
    if (b < 256) {
        __shared__ float xs[4][C], ts[4][C];
        int p0 = b * 4;
        int c = tid & 127, pp = tid >> 7;
#pragma unroll
        for (int q = 0; q < 2; q++) {
            int px = pp * 2 + q;
            int p = p0 + px;
            int h = p >> 5, w = p & 31;
            xs[px][c] = x[(size_t)p * C + c];
            float y = dw_b[c];
#pragma unroll
            for (int dy = 0; dy < 3; dy++) {
                int hh = h + dy - 1;
                if (hh < 0 || hh >= H) continue;
#pragma unroll
                for (int dx = 0; dx < 3; dx++) {
                    int wq = w + dx - 1;
                    if (wq < 0 || wq >= W) continue;
                    y = fmaf(x[((size_t)hh * W + wq) * C + c], dw_k[(dy * 3 + dx) * C + c], y);
                }
            }
            ts[px][c] = siluf_(y);
        }
        __syncthreads();
        float ap0 = b_in[c], ap1 = ap0, ad0 = pw_b[c], ad1 = ad0;
        int b0 = pp * 2, b1 = pp * 2 + 1;
        for (int i = 0; i < C; i += 4) {
#pragma unroll
            for (int u = 0; u < 4; u++) {
                float wi = w_in[(size_t)(i + u) * C + c];
                float pi = pw_w[(size_t)(i + u) * C + c];
                ap0 = fmaf(xs[b0][i + u], wi, ap0);
                ap1 = fmaf(xs[b1][i + u], wi, ap1);
                ad0 = fmaf(ts[b0][i + u], pi, ad0);
                ad1 = fmaf(ts[b1][i + u], pi, ad1);
            }
        }
        ws[WS_XPROJ + (size_t)(p0 + b0) * C + c] = ap0;
        ws[WS_XPROJ + (size_t)(p0 + b1) * C + c] = ap1;
        ws[WS_XDW  + (size_t)(p0 + b0) * C + c] = ad0;
        ws[WS_XDW  + (size_t)(p0 + b1) * C + c] = ad1;
    } else {
        int mb = b - 256;   // 0..56
        if (mb == 0) {
            __shared__ float red[256];
            float xsg = raw_sigma[0];
            float sp = fmaxf(xsg, 0.f) + log1pf(expf(-fabsf(xsg)));
            float sigma = fminf(fmaxf(sp, 0.001f), 0.5f);
            float inv2s2 = 1.f / (2.f * sigma * sigma);
            int i = tid / 15, j = tid % 15;
            float e = 0.f;
            if (tid < K2) {
                float gi = -0.5f + (float)i * (1.f / 14.f);
                float gj = -0.5f + (float)j * (1.f / 14.f);
                e = expf(-(gi * gi + gj * gj) * inv2s2);
            }
            red[tid] = e;
            __syncthreads();
            for (int s = 128; s > 0; s >>= 1) {
                if (tid < s) red[tid] += red[tid + s];
                __syncthreads();
            }
            float esum = fmaxf(red[0], 1e-8f);
            if (tid < K2) ws[WS_ENV + tid] = e / esum;
            if (tid < 64) mlp_point(224, tid, k1_w, k1_b, k2_w, k2_b, k3_w, k3_b, ws);
        } else {
            int k2i = (mb - 1) * 4 + (tid >> 6);  // 0..223
            mlp_point(k2i, tid & 63, k1_w, k1_b, k2_w, k2_b, k3_w, k3_b, ws);
        }
    }
}

// ---------------- K2: offs+mask GEMM, 128x128 tile, 8x8 per thread ----------------
__global__ __launch_bounds__(256) void offmsk_gemm(const float* __restrict__ A,
        const float* __restrict__ off_w, const float* __restrict__ off_b,
        const float* __restrict__ msk_w, const float* __restrict__ msk_b,
        const float* __restrict__ bos, const float* __restrict__ env,
        float* __restrict__ offs_out, float* __restrict__ mask_out) {
    __shared__ float At[32][132];   // transposed A tile (k-major)
    __shared__ float Bs[32][128];
    int tid = threadIdx.x;
    int c0 = blockIdx.x * 128;
    int p0 = blockIdx.y * 128;
    int tx = tid & 15, ty = tid >> 4;

    float acc[8][8];
#pragma unroll
    for (int i = 0; i < 8; i++)
#pragma unroll
        for (int j = 0; j < 8; j++) acc[i][j] = 0.f;

    int cL = (tid & 31) * 4;
    int kB = tid >> 5;                 // 0..7
    int cB = c0 + cL;
    const float* bptr = nullptr; int bstride = 0;
    if (cB < NOFF)       { bptr = off_w + cB;          bstride = NOFF; }
    else if (cB < NTOT)  { bptr = msk_w + (cB - NOFF); bstride = NMSK; }
    int rA = tid >> 3, k4A = (tid & 7) * 4;

    for (int kt = 0; kt < C; kt += 32) {
        if (kt) __syncthreads();
#pragma unroll
        for (int pass = 0; pass < 4; pass++) {
            int r = rA + pass * 32;
            float4 v = *(const float4*)&A[(size_t)(p0 + r) * C + kt + k4A];
            At[k4A + 0][r] = v.x; At[k4A + 1][r] = v.y;
            At[k4A + 2][r] = v.z; At[k4A + 3][r] = v.w;
        }
#pragma unroll
        for (int pass = 0; pass < 4; pass++) {
            int k = kB + pass * 8;
            float4 bv = make_float4(0.f, 0.f, 0.f, 0.f);
            if (bptr) bv = *(const float4*)&bptr[(size_t)(kt + k) * bstride];
            *(float4*)&Bs[k][cL] = bv;
        }
        __syncthreads();
#pragma unroll 4
        for (int k = 0; k < 32; k++) {
            float4 a0 = *(const float4*)&At[k][ty * 8];
            float4 a1 = *(const float4*)&At[k][ty * 8 + 4];
            float4 b0 = *(const float4*)&Bs[k][tx * 8];
            float4 b1 = *(const float4*)&Bs[k][tx * 8 + 4];
            const float av[8] = {a0.x, a0.y, a0.z, a0.w, a1.x, a1.y, a1.z, a1.w};
            const float bv[8] = {b0.x, b0.y, b0.z, b0.w, b1.x, b1.y, b1.z, b1.w};
#pragma unroll
            for (int i = 0; i < 8; i++)
#pragma unroll
                for (int j = 0; j < 8; j++)
                    acc[i][j] = fmaf(av[i], bv[j], acc[i][j]);
        }
    }

    int colbase = c0 + tx * 8;     // 1800 % 8 == 0 -> no region straddle
    if (colbase >= NTOT) return;
    bool full = (colbase + 8) <= NTOT;
    float bias[8], sc[8];
    float* obase;
    int ostride;
    if (colbase < NOFF) {
        float s = bos[0];
#pragma unroll
        for (int j = 0; j < 8; j++) { bias[j] = off_b[colbase + j]; sc[j] = s; }
        obase = offs_out + colbase; ostride = NOFF;
    } else {
        int m0 = colbase - NOFF;
#pragma unroll
        for (int j = 0; j < 8; j++) {
            if (colbase + j < NTOT) { bias[j] = msk_b[m0 + j]; sc[j] = env[(m0 + j) % K2]; }
            else                    { bias[j] = 0.f; sc[j] = 0.f; }
        }
        obase = mask_out + m0; ostride = NMSK;
    }
#pragma unroll
    for (int i = 0; i < 8; i++) {
        size_t row = (size_t)(p0 + ty * 8 + i);
        if (full) {
            float4 r0 = make_float4((acc[i][0] + bias[0]) * sc[0], (acc[i][1] + bias[1]) * sc[1],
                                    (acc[i][2] + bias[2]) * sc[2], (acc[i][3] + bias[3]) * sc[3]);
            float4 r1 = make_float4((acc[i][4] + bias[4]) * sc[4], (acc[i][5] + bias[5]) * sc[5],
                                    (acc[i][6] + bias[6]) * sc[6], (acc[i][7] + bias[7]) * sc[7]);
            *(float4*)&obase[row * ostride]     = r0;
            *(float4*)&obase[row * ostride + 4] = r1;
        } else {
#pragma unroll
            for (int j = 0; j < 8; j++)
                if (colbase + j < NTOT)
                    obase[row * ostride + j] = (acc[i][j] + bias[j]) * sc[j];
        }
    }
}

// ---------------- K3: sampler (2 px/block) + pooled partial write ----------------
__global__ __launch_bounds__(256) void sampler_kernel(const float* __restrict__ ws_offs,
        const float* __restrict__ ws_mask, const float* __restrict__ xproj,
        const float* __restrict__ kwf, float* __restrict__ outpre,
        float* __restrict__ partial) {
    int blk = blockIdx.x;
    int p0 = blk * 2;
    int h = p0 >> 5;
    int tid = threadIdx.x;

    __shared__ float   attn_s[2][NMSK];
    __shared__ float4  wgt_s[2][NMSK];
    __shared__ ushort4 loc_s[2][NMSK];
    __shared__ float   outp[2][C];

    // phase 1: softmax per (px,g) on 8 half-waves
    {
        int half = tid >> 5;
        int l32 = tid & 31;
        int px = half >> 2, g = half & 3;
        const float* mrow = ws_mask + (size_t)(p0 + px) * NMSK + g * K2;
        float v[8];
        float mx = -1e30f;
#pragma unroll
        for (int q = 0; q < 8; q++) {
            int k = l32 + q * 32;
            v[q] = (k < K2) ? mrow[k] : -1e30f;
            mx = fmaxf(mx, v[q]);
        }
#pragma unroll
        for (int s = 16; s > 0; s >>= 1) mx = fmaxf(mx, __shfl_xor(mx, s));
        float sum = 0.f;
#pragma unroll
        for (int q = 0; q < 8; q++) {
            int k = l32 + q * 32;
            v[q] = (k < K2) ? expf(v[q] - mx) : 0.f;
            sum += v[q];
        }
#pragma unroll
        for (int s = 16; s > 0; s >>= 1) sum += __shfl_xor(sum, s);
        float inv = 1.f / sum;
#pragma unroll
        for (int q = 0; q < 8; q++) {
            int k = l32 + q * 32;
            if (k < K2) attn_s[px][g * K2 + k] = v[q] * inv;
        }
    }
    __syncthreads();

    // phase 2: bilinear weights (attn*valid folded) + packed corner pixel indices
    for (int e = tid; e < 2 * NMSK; e += 256) {
        int px = (e >= NMSK) ? 1 : 0;
        int m = e - px * NMSK;
        int g = m / K2;
        int k = m - g * K2;
        int p = p0 + px;
        int w = p & 31;
        float2 o = *(const float2*)&ws_offs[(size_t)p * NOFF + m * 2];
        float abs_h = (float)(h + k / 15 - 7) + o.x;
        float abs_w = (float)(w + k % 15 - 7) + o.y;
        float validf = (abs_h < 0.f || abs_h > 31.f || abs_w < 0.f || abs_w > 31.f) ? 0.f : 1.f;
        float ah = fminf(fmaxf(abs_h, 0.f), 31.f);
        float aw = fminf(fmaxf(abs_w, 0.f), 31.f);
        int hf = (int)ah, wf = (int)aw;
        int hc = min(hf + 1, 31), wc = min(wf + 1, 31);
        float hwt = ah - (float)hf, wwt = aw - (float)wf;
        float a = attn_s[px][m] * validf;
        float u0 = 1.f - hwt, u1 = 1.f - wwt;
        wgt_s[px][m] = make_float4(a * u0 * u1, a * u0 * wwt, a * hwt * u1, a * hwt * wwt);
        loc_s[px][m] = make_ushort4((unsigned short)(hf * W + wf), (unsigned short)(hf * W + wc),
                                    (unsigned short)(hc * W + wf), (unsigned short)(hc * W + wc));
    }
    __syncthreads();

    // phase 3: px(2) x g(4) x s(4) x cq(8), shuffle-reduce over s
    {
        int cq = tid & 7;
        int s  = (tid >> 3) & 3;
        int g  = (tid >> 5) & 3;
        int px = tid >> 7;
        int k0 = (s * K2) >> 2;
        int k1 = ((s + 1) * K2) >> 2;
        const float* xpg = xproj + g * GC + cq * 4;
        const float* kwg = kwf + (size_t)g * (K2 * GC) + cq * 4;
        float4 acc = make_float4(0.f, 0.f, 0.f, 0.f);
#pragma unroll 2
        for (int k = k0; k < k1; k++) {
            int m = g * K2 + k;
            ushort4 L  = loc_s[px][m];
            float4  Wv = wgt_s[px][m];
            float4 x00 = *(const float4*)(xpg + (int)L.x * C);
            float4 x01 = *(const float4*)(xpg + (int)L.y * C);
            float4 x10 = *(const float4*)(xpg + (int)L.z * C);
            float4 x11 = *(const float4*)(xpg + (int)L.w * C);
            float4 kw4 = *(const float4*)(kwg + k * GC);
            float sx = fmaf(Wv.w, x11.x, fmaf(Wv.z, x10.x, fmaf(Wv.y, x01.x, Wv.x * x00.x)));
            float sy = fmaf(Wv.w, x11.y, fmaf(Wv.z, x10.y, fmaf(Wv.y, x01.y, Wv.x * x00.y)));
            float sz = fmaf(Wv.w, x11.z, fmaf(Wv.z, x10.z, fmaf(Wv.y, x01.z, Wv.x * x00.z)));
            float sw = fmaf(Wv.w, x11.w, fmaf(Wv.z, x10.w, fmaf(Wv.y, x01.w, Wv.x * x00.w)));
            acc.x = fmaf(kw4.x, sx, acc.x);
            acc.y = fmaf(kw4.y, sy, acc.y);
            acc.z = fmaf(kw4.z, sz, acc.z);
            acc.w = fmaf(kw4.w, sw, acc.w);
        }
        acc.x += __shfl_xor(acc.x, 8);  acc.y += __shfl_xor(acc.y, 8);
        acc.z += __shfl_xor(acc.z, 8);  acc.w += __shfl_xor(acc.w, 8);
        acc.x += __shfl_xor(acc.x, 16); acc.y += __shfl_xor(acc.y, 16);
        acc.z += __shfl_xor(acc.z, 16); acc.w += __shfl_xor(acc.w, 16);
        if (s == 0) {
            *(float4*)&outp[px][g * GC + cq * 4] = acc;
            *(float4*)&outpre[(size_t)(p0 + px) * C + g * GC + cq * 4] = acc;
        }
    }
    __syncthreads();
    if (tid < C)
        partial[(size_t)blk * C + tid] = outp[0][tid] + outp[1][tid];
}

// ---------------- K4: redundant pooled reduce + SE MLP + final GEMV (4 px/block) ----------------
__global__ __launch_bounds__(256) void finale_kernel(const float* __restrict__ outpre,
        const float* __restrict__ partial,
        const float* __restrict__ se1_w, const float* __restrict__ se1_b,
        const float* __restrict__ se2_w, const float* __restrict__ se2_b,
        const float* __restrict__ w_out, const float* __restrict__ b_out,
        float* __restrict__ out) {
    int tid = threadIdx.x;
    __shared__ float tmp[8][132];
    __shared__ float pooled[C];
    __shared__ float hid[KHID];
    __shared__ float scl[C];
    __shared__ float v[4][C];

    // pooled reduce: 8 block-groups x 32 channel-quads, coalesced float4 reads
    {
        int bg = tid >> 5, c4 = (tid & 31) * 4;
        float4 s4 = make_float4(0.f, 0.f, 0.f, 0.f);
        for (int i = 0; i < 64; i++) {
            float4 pv = *(const float4*)&partial[(size_t)(bg * 64 + i) * C + c4];
            s4.x += pv.x; s4.y += pv.y; s4.z += pv.z; s4.w += pv.w;
        }
        *(float4*)&tmp[bg][c4] = s4;
    }
    __syncthreads();
    if (tid < C) {
        float s = 0.f;
#pragma unroll
        for (int g = 0; g < 8; g++) s += tmp[g][tid];
        pooled[tid] = s * (1.f / 1024.f);
    }
    __syncthreads();
    if (tid < KHID) {
        float a = se1_b[tid];
        for (int cc = 0; cc < C; cc++) a = fmaf(pooled[cc], se1_w[cc * KHID + tid], a);
        hid[tid] = siluf_(a);
    }
    __syncthreads();
    if (tid < C) {
        float a = se2_b[tid];
#pragma unroll
        for (int q = 0; q < KHID; q++) a = fmaf(hid[q], se2_w[q * C + tid], a);
        scl[tid] = sigmoidf_(a);
    }
    __syncthreads();

    int p0 = blockIdx.x * 4;
    int c = tid & 127, pp = tid >> 7;
#pragma unroll
    for (int q = 0; q < 2; q++) {
        int px = pp * 2 + q;
        v[px][c] = outpre[(size_t)(p0 + px) * C + c] * scl[c];
    }
    __syncthreads();
    float a0 = b_out[c], a1 = b_out[c];
    int b0 = pp * 2, b1 = pp * 2 + 1;
    for (int i = 0; i < C; i += 4) {
#pragma unroll
        for (int u = 0; u < 4; u++) {
            float wv = w_out[(size_t)(i + u) * C + c];
            a0 = fmaf(v[b0][i + u], wv, a0);
            a1 = fmaf(v[b1][i + u], wv, a1);
        }
    }
    out[(size_t)(p0 + b0) * C + c] = a0;
    out[(size_t)(p0 + b1) * C + c] = a1;
}

extern "C" void kernel_launch(void* const* d_in, const int* in_sizes, int n_in,
                              void* d_out, int out_size, void* d_ws, size_t ws_size,
                              hipStream_t stream) {
    const float* x         = (const float*)d_in[0];
    const float* raw_sigma = (const float*)d_in[1];
    const float* bos       = (const float*)d_in[2];
    const float* w_in      = (const float*)d_in[3];
    const float* b_in      = (const float*)d_in[4];
    const float* w_out     = (const float*)d_in[5];
    const float* b_out     = (const float*)d_in[6];
    const float* dw_k      = (const float*)d_in[7];
    const float* dw_b      = (const float*)d_in[8];
    const float* pw_w      = (const float*)d_in[9];
    const float* pw_b      = (const float*)d_in[10];
    const float* off_w     = (const float*)d_in[11];
    const float* off_b     = (const float*)d_in[12];
    const float* msk_w     = (const float*)d_in[13];
    const float* msk_b     = (const float*)d_in[14];
    const float* k1_w      = (const float*)d_in[15];
    const float* k1_b      = (const float*)d_in[16];
    const float* k2_w      = (const float*)d_in[17];
    const float* k2_b      = (const float*)d_in[18];
    const float* k3_w      = (const float*)d_in[19];
    const float* k3_b      = (const float*)d_in[20];
    const float* se1_w     = (const float*)d_in[21];
    const float* se1_b     = (const float*)d_in[22];
    const float* se2_w     = (const float*)d_in[23];
    const float* se2_b     = (const float*)d_in[24];

    float* ws  = (float*)d_ws;
    float* out = (float*)d_out;

    prep_front_kernel<<<313, 256, 0, stream>>>(x, raw_sigma, w_in, b_in, dw_k, dw_b,
                                               pw_w, pw_b, k1_w, k1_b, k2_w, k2_b,
                                               k3_w, k3_b, ws);

    dim3 gg((NTOT + 127) / 128, NPIX / 128);   // 22 x 8
    offmsk_gemm<<<gg, 256, 0, stream>>>(ws + WS_XDW, off_w, off_b, msk_w, msk_b, bos,
                                        ws + WS_ENV, ws + WS_OFFS, ws + WS_MASK);

    sampler_kernel<<<NPIX / 2, 256, 0, stream>>>(ws + WS_OFFS, ws + WS_MASK, ws + WS_XPROJ,
                                                 ws + WS_KW, ws + WS_OUTPRE, ws + WS_PART);

    finale_kernel<<<NPIX / 4, 256, 0, stream>>>(ws + WS_OUTPRE, ws + WS_PART,
                                                se1_w, se1_b, se2_w, se2_b,
                                                w_out, b_out, out);
}